// Round 17
// baseline (187.661 us; speedup 1.0000x reference)
//
#include <hip/hip_runtime.h>
#include <stdint.h>

#define DEV __device__ __forceinline__

typedef __attribute__((ext_vector_type(4))) float f32x4;
typedef __attribute__((ext_vector_type(16))) float f32x16;
typedef __attribute__((ext_vector_type(8))) __bf16 bf16x8;
typedef __attribute__((ext_vector_type(4))) __bf16 bf16x4;
typedef __attribute__((ext_vector_type(8))) short short8;
typedef __attribute__((ext_vector_type(4))) unsigned short u16x4;

DEV unsigned short f2bf_n(float f) {
    __bf16 h = (__bf16)f;
    return __builtin_bit_cast(unsigned short, h);
}
DEV bf16x8 ld8(const unsigned short* p) {
    short8 v = *(const short8*)p;
    return __builtin_bit_cast(bf16x8, v);
}
DEV void ldsdma16(unsigned short* lds, const unsigned short* g) {
    __builtin_amdgcn_global_load_lds(
        (const __attribute__((address_space(1))) unsigned int*)g,
        (__attribute__((address_space(3))) unsigned int*)lds, 16, 0, 0);
}

// ---------------------------------------------------------------------------
// Token compaction with parallel (Hillis-Steele) scan.
// sidx[b][j] = s of j-th unmasked token; hdr[b]=nb, hdr[2+b]=nbp (pad 128).
// ---------------------------------------------------------------------------
__global__ __launch_bounds__(256) void compact_kernel(
    const float* __restrict__ mask, int* __restrict__ sidx, int* __restrict__ hdr)
{
    __shared__ int part[256];
    const int b = blockIdx.x, t = threadIdx.x;
    int loc[8], cnt = 0;
#pragma unroll
    for (int k = 0; k < 8; ++k) {
        loc[k] = (mask[b * 2048 + t * 8 + k] > 0.5f) ? 1 : 0;
        cnt += loc[k];
    }
    part[t] = cnt;
    __syncthreads();
#pragma unroll
    for (int off = 1; off < 256; off <<= 1) {
        int v = (t >= off) ? part[t - off] : 0;
        __syncthreads();
        part[t] += v;
        __syncthreads();
    }
    const int total = part[255];
    if (t == 0) {
        hdr[b] = total;
        hdr[2 + b] = (total + 127) & ~127;
    }
    int base = part[t] - cnt;            // exclusive prefix
#pragma unroll
    for (int k = 0; k < 8; ++k)
        if (loc[k]) sidx[b * 2048 + (base++)] = t * 8 + k;
    for (int j = total + t; j < 2048; j += 256) sidx[b * 2048 + j] = -1;
}

// ---------------------------------------------------------------------------
// Fused prep: grid 12288 blocks x 256 thr, three block ranges co-scheduled:
//   [0,4096)     gather+convert X row -> compact Xc (zero pad rows)
//   [4096,8192)  out init: every token's out row = bo
//   [8192,12288) W f32 -> bf16 (Wq|Wk|Wv|Wo)
// ---------------------------------------------------------------------------
__global__ __launch_bounds__(256) void prep_kernel(
    const float* __restrict__ X, const float* __restrict__ mask_unused,
    const float* __restrict__ Wq, const float* __restrict__ Wk,
    const float* __restrict__ Wv, const float* __restrict__ Wo,
    const float* __restrict__ bo, const int* __restrict__ sidx,
    const int* __restrict__ hdr,
    unsigned short* __restrict__ Xc, unsigned short* __restrict__ Wb,
    float* __restrict__ out)
{
    const int bx = blockIdx.x, t = threadIdx.x;
    if (bx < 4096) {
        const int b = bx >> 11, j = bx & 2047;
        if (j >= hdr[2 + b]) return;
        const int col = t * 4;
        bf16x4 o;
        if (j < hdr[b]) {
            int s = sidx[b * 2048 + j];
            f32x4 v = *(const f32x4*)&X[(size_t)(b * 2048 + s) * 1024 + col];
            o = (bf16x4){ (__bf16)v[0], (__bf16)v[1], (__bf16)v[2], (__bf16)v[3] };
        } else {
            o = (bf16x4){ (__bf16)0.f, (__bf16)0.f, (__bf16)0.f, (__bf16)0.f };
        }
        *(bf16x4*)&Xc[(size_t)bx * 1024 + col] = o;
    } else if (bx < 8192) {
        int row = bx - 4096;
        int e = t * 4;
        f32x4 v = *(const f32x4*)&bo[e];
        *(f32x4*)&out[(size_t)row * 1024 + e] = v;
    } else {
        int c = (bx - 8192) * 256 + t;
        int wsel = c >> 18, off = (c & 262143) * 4;
        const float* ws_[4] = { Wq, Wk, Wv, Wo };
        f32x4 v = *(const f32x4*)(ws_[wsel] + off);
        bf16x4 b = { (__bf16)v[0], (__bf16)v[1], (__bf16)v[2], (__bf16)v[3] };
        *(bf16x4*)&Wb[wsel * 1048576 + off] = b;
    }
}

// ---------------------------------------------------------------------------
// Fused QKV projection on COMPACT rows (256 thr, BK=64 single-buffer DMA
// staging). Blocks beyond nbp(b) exit. grid (32, 24). [UNCHANGED]
// ---------------------------------------------------------------------------
__global__ __launch_bounds__(256) void qkv_kernel(
    const unsigned short* __restrict__ Xc, const unsigned short* __restrict__ Wb,
    const float* __restrict__ bq, const float* __restrict__ bk,
    const float* __restrict__ bv, const int* __restrict__ hdr,
    unsigned short* __restrict__ Qc, unsigned short* __restrict__ Kc,
    unsigned short* __restrict__ VTc)
{
    __shared__ __align__(16) unsigned short SMEM[17408];
    unsigned short* As = SMEM;
    unsigned short* Bs = SMEM + 8192;

    const int m0 = blockIdx.x * 128;
    const int b = m0 >> 11;
    if ((m0 & 2047) >= hdr[2 + b]) return;

    const int t = threadIdx.x;
    const int lane = t & 63, w = t >> 6;
    const int wm = w & 1, wn = w >> 1;
    const int l15 = lane & 15, grp = lane >> 4;
    const int which = blockIdx.y >> 3;
    const int e0 = (blockIdx.y & 7) * 128;

    const unsigned short* Wmat = Wb + which * 1048576;
    const float* bias = (which == 0) ? bq : (which == 1) ? bk : bv;

    const int srow = lane >> 3, sc_ = lane & 7;

    f32x4 acc[4][4];
#pragma unroll
    for (int i = 0; i < 4; ++i)
#pragma unroll
        for (int j = 0; j < 4; ++j) acc[i][j] = (f32x4){0.f, 0.f, 0.f, 0.f};

    for (int kt = 0; kt < 16; ++kt) {
        const int k0 = kt * 64;
        __syncthreads();
#pragma unroll
        for (int j = 0; j < 4; ++j) {
            int row = (w * 4 + j) * 8 + srow;
            int cs = sc_ ^ (row & 7);
            ldsdma16(&As[(w * 4 + j) * 512],
                     &Xc[(m0 + row) * 1024 + k0 + cs * 8]);
            ldsdma16(&Bs[(w * 4 + j) * 512],
                     &Wmat[(e0 + row) * 1024 + k0 + cs * 8]);
        }
        __syncthreads();
#pragma unroll
        for (int kk = 0; kk < 64; kk += 32) {
            const int cb = kk >> 3;
            bf16x8 af[4], bfr[4];
#pragma unroll
            for (int i = 0; i < 4; ++i) {
                int r = wm * 64 + i * 16 + l15;
                af[i] = ld8(&As[r * 64 + (((cb + grp) ^ (r & 7)) << 3)]);
            }
#pragma unroll
            for (int j = 0; j < 4; ++j) {
                int r = wn * 64 + j * 16 + l15;
                bfr[j] = ld8(&Bs[r * 64 + (((cb + grp) ^ (r & 7)) << 3)]);
            }
#pragma unroll
            for (int i = 0; i < 4; ++i)
#pragma unroll
                for (int j = 0; j < 4; ++j)
                    acc[i][j] = __builtin_amdgcn_mfma_f32_16x16x32_bf16(
                        af[i], bfr[j], acc[i][j], 0, 0, 0);
        }
    }

    __syncthreads();

    if (which == 2) {
#pragma unroll
        for (int j = 0; j < 4; ++j) {
            int e = e0 + wn * 64 + j * 16 + l15;
            float bv_ = bias[e];
#pragma unroll
            for (int i = 0; i < 4; ++i) {
                u16x4 pk;
#pragma unroll
                for (int r = 0; r < 4; ++r) pk[r] = f2bf_n(acc[i][j][r] + bv_);
                *(u16x4*)&SMEM[(wn * 64 + j * 16 + l15) * 136 +
                               wm * 64 + i * 16 + grp * 4] = pk;
            }
        }
        __syncthreads();
        const int s0 = m0 & 2047;
#pragma unroll
        for (int round = 0; round < 8; ++round) {
            int dhl = (t >> 4) + round * 16;
            int chunk = t & 15;
            int h = (e0 + dhl) >> 6, dh = (e0 + dhl) & 63;
            *(short8*)&VTc[((b * 16 + h) * 64 + dh) * 2048 + s0 + chunk * 8] =
                *(const short8*)&SMEM[dhl * 136 + chunk * 8];
        }
    } else {
        const float scale = (which == 0) ? 0.125f : 1.0f;
#pragma unroll
        for (int j = 0; j < 4; ++j) {
            int e = e0 + wn * 64 + j * 16 + l15;
            float bv_ = bias[e];
#pragma unroll
            for (int i = 0; i < 4; ++i)
#pragma unroll
                for (int r = 0; r < 4; ++r)
                    SMEM[(wm * 64 + i * 16 + grp * 4 + r) * 136 +
                         wn * 64 + j * 16 + l15] =
                        f2bf_n((acc[i][j][r] + bv_) * scale);
        }
        __syncthreads();
        unsigned short* dst = (which == 0) ? Qc : Kc;
#pragma unroll
        for (int round = 0; round < 8; ++round) {
            int tl = (t >> 4) + round * 16;
            int chunk = t & 15;
            int e = e0 + chunk * 8;
            int h = e >> 6, dh = e & 63;
            int s = (m0 & 2047) + tl;
            *(short8*)&dst[((b * 16 + h) * 2048 + s) * 64 + dh] =
                *(const short8*)&SMEM[tl * 136 + chunk * 8];
        }
    }
}

// ---------------------------------------------------------------------------
// Flash attention v6-compact: 64 q-rows/block + 4-way split-K on COMPACT
// tokens. grid (32, 32), 512 thr (qg = w&1, ksub = w>>1). With nbp~1024,
// active q-blocks/head = nbp/64 ~ 16 = the multiplicity measured cache-safe
// (rounds 8-12); occupancy 1 -> 2 blocks/CU vs the 128-row version.
// LDS 53,248 B. Staged 2-round merge (round 13: canary-preserving).
// ---------------------------------------------------------------------------
__global__ __launch_bounds__(512, 4) void attn_kernel(
    const unsigned short* __restrict__ Qc, const unsigned short* __restrict__ Kc,
    const unsigned short* __restrict__ VTc, const int* __restrict__ hdr,
    unsigned short* __restrict__ Xattn)
{
    __shared__ __align__(16) unsigned short SMEM[26624];   // 53,248 B
    unsigned short* Ks = SMEM;                    // [key][dh],  8-chunk swizzle
    unsigned short* Vs = SMEM + 8192;             // [dh][key], 16-chunk swizzle
    unsigned short* Ps = SMEM + 16384;            // per-wave 32x40 strips
    float* mrg = (float*)SMEM;                    // merge overlay (49,152 B)

    const int bh = blockIdx.y;
    const int b = bh >> 4;
    const int nbl = hdr[b], nbpl = hdr[2 + b];
    const int q0 = blockIdx.x * 64;
    if (q0 >= nbpl) return;

    const int t = threadIdx.x;
    const int lane = t & 63, w = t >> 6;          // 8 waves
    const int l31 = lane & 31, half = lane >> 5;
    const int qg = w & 1, ksub = w >> 1;          // 2 q-groups x 4 key-subsets

    const unsigned short* Kp = Kc + (size_t)bh * 131072;
    const unsigned short* Vp = VTc + (size_t)bh * 131072;

    bf16x8 qf[4];
#pragma unroll
    for (int s = 0; s < 4; ++s)
        qf[s] = ld8(&Qc[(bh * 2048 + q0 + qg * 32 + l31) * 64 + s * 16 + half * 8]);

    short onev = (l31 == 0) ? (short)0x3F80 : (short)0;
    short8 ov = { onev, onev, onev, onev, onev, onev, onev, onev };
    bf16x8 ones_f = __builtin_bit_cast(bf16x8, ov);

    unsigned short* Pw = Ps + w * 1280;           // this wave's 32x40 strip

    f32x16 accd[2], accl;
#pragma unroll
    for (int d = 0; d < 2; ++d)
#pragma unroll
        for (int r = 0; r < 16; ++r) accd[d][r] = 0.f;
#pragma unroll
    for (int r = 0; r < 16; ++r) accl[r] = 0.f;

    const int nkb = nbpl >> 7;
    for (int kb = 0; kb < nkb; ++kb) {
        const int k0 = kb * 128;
        __syncthreads();                 // prev tile's readers done
#pragma unroll
        for (int ii = 0; ii < 2; ++ii) { // Ks: 16 DMA (8 rows x 128B), 2/wave
            int inst = w * 2 + ii;
            int row = inst * 8 + (lane >> 3);
            int cs = (lane & 7) ^ (row & 7);
            ldsdma16(&Ks[inst * 512], &Kp[(k0 + row) * 64 + cs * 8]);
        }
#pragma unroll
        for (int ii = 0; ii < 2; ++ii) { // Vs: 16 DMA (4 rows x 256B), 2/wave
            int inst = w * 2 + ii;
            int row = inst * 4 + (lane >> 4);
            int cs = (lane & 15) ^ (row & 15);
            ldsdma16(&Vs[inst * 512], &Vp[row * 2048 + k0 + cs * 8]);
        }
        float mc = (k0 + ksub * 32 + l31 < nbl) ? 1.f : 0.f;
        __syncthreads();                 // DMA drained

        // S = Q.K^T over this wave's 32 keys
        f32x16 z;
#pragma unroll
        for (int r = 0; r < 16; ++r) z[r] = 0.f;
        int rK = ksub * 32 + l31;
#pragma unroll
        for (int s = 0; s < 4; ++s) {
            int chunk = s * 2 + half;
            bf16x8 kf = ld8(&Ks[rK * 64 + ((chunk ^ (rK & 7)) << 3)]);
            z = __builtin_amdgcn_mfma_f32_32x32x16_bf16(qf[s], kf, z, 0, 0, 0);
        }
        // P = exp(s)*m into wave-private strip (col = l31)
#pragma unroll
        for (int r = 0; r < 16; ++r) {
            float p = __expf(z[r]) * mc;
            int ql = (r & 3) + 8 * (r >> 2) + 4 * half;
            Pw[ql * 40 + l31] = f2bf_n(p);
        }
        // wave-private: in-wave lgkmcnt ordering, no barrier
        bf16x8 pf[2];
#pragma unroll
        for (int sp = 0; sp < 2; ++sp)
            pf[sp] = ld8(&Pw[l31 * 40 + sp * 16 + half * 8]);
        // PV + ones over this wave's key chunk
#pragma unroll
        for (int d = 0; d < 2; ++d) {
            int rV = d * 32 + l31;
#pragma unroll
            for (int sp = 0; sp < 2; ++sp) {
                int chunk = ksub * 4 + sp * 2 + half;
                bf16x8 vf = ld8(&Vs[rV * 128 + ((chunk ^ (rV & 15)) << 3)]);
                accd[d] = __builtin_amdgcn_mfma_f32_32x32x16_bf16(
                    pf[sp], vf, accd[d], 0, 0, 0);
            }
        }
#pragma unroll
        for (int sp = 0; sp < 2; ++sp)
            accl = __builtin_amdgcn_mfma_f32_32x32x16_bf16(
                pf[sp], ones_f, accl, 0, 0, 0);
    }

    // ---- 4-way split-K merge, staged (peak overlay 49,152 B) ----
    __syncthreads();
    if (ksub >= 2) {                     // round A writers: ksub 2,3
        float* q_ = mrg + (qg * 2 + (ksub - 2)) * 3072;   // [48][64] f32
#pragma unroll
        for (int r = 0; r < 16; ++r) {
            q_[(r) * 64 + lane]      = accd[0][r];
            q_[(16 + r) * 64 + lane] = accd[1][r];
            q_[(32 + r) * 64 + lane] = accl[r];
        }
    }
    __syncthreads();
    if (ksub < 2) {                      // round A adders: ksub 0,1
        const float* q_ = mrg + (qg * 2 + ksub) * 3072;
#pragma unroll
        for (int r = 0; r < 16; ++r) {
            accd[0][r] += q_[(r) * 64 + lane];
            accd[1][r] += q_[(16 + r) * 64 + lane];
            accl[r]    += q_[(32 + r) * 64 + lane];
        }
    }
    __syncthreads();
    if (ksub == 1) {                     // round B writer
        float* q_ = mrg + qg * 3072;
#pragma unroll
        for (int r = 0; r < 16; ++r) {
            q_[(r) * 64 + lane]      = accd[0][r];
            q_[(16 + r) * 64 + lane] = accd[1][r];
            q_[(32 + r) * 64 + lane] = accl[r];
        }
    }
    __syncthreads();
    if (ksub == 0) {                     // round B adder + epilogue
        const float* q_ = mrg + qg * 3072;
#pragma unroll
        for (int r = 0; r < 16; ++r) {
            accd[0][r] += q_[(r) * 64 + lane];
            accd[1][r] += q_[(16 + r) * 64 + lane];
            accl[r]    += q_[(32 + r) * 64 + lane];
        }
#pragma unroll
        for (int r = 0; r < 16; ++r) {
            int ql = (r & 3) + 8 * (r >> 2) + 4 * half;
            int j = q0 + qg * 32 + ql;
            float lr = __shfl(accl[r], half * 32, 64);
            float inv = 1.f / (lr + 1e-13f);
#pragma unroll
            for (int d = 0; d < 2; ++d)
                Xattn[(b * 2048 + j) * 1024 + (bh & 15) * 64 + d * 32 + l31] =
                    f2bf_n(accd[d][r] * inv);
        }
    }
}

// ---------------------------------------------------------------------------
// Output projection on COMPACT rows, scatter via sidx. grid (64, 8).
// [UNCHANGED]
// ---------------------------------------------------------------------------
__global__ __launch_bounds__(256) void oproj_kernel(
    const unsigned short* __restrict__ A, const unsigned short* __restrict__ W,
    const float* __restrict__ bias, const int* __restrict__ sidx,
    const int* __restrict__ hdr, float* __restrict__ out)
{
    __shared__ __align__(16) unsigned short As[64 * 64];
    __shared__ __align__(16) unsigned short Bs[128 * 64];

    const int m0 = blockIdx.x * 64;
    const int b = m0 >> 11;
    const int nbl = hdr[b];
    if ((m0 & 2047) >= hdr[2 + b]) return;

    const int t = threadIdx.x;
    const int lane = t & 63, w = t >> 6;
    const int l15 = lane & 15, grp = lane >> 4;
    const int e0 = blockIdx.y * 128;
    const int srow = lane >> 3, sc_ = lane & 7;

    f32x4 acc[4][2];
#pragma unroll
    for (int i = 0; i < 4; ++i)
#pragma unroll
        for (int j = 0; j < 2; ++j) acc[i][j] = (f32x4){0.f, 0.f, 0.f, 0.f};

    for (int kt = 0; kt < 16; ++kt) {
        const int k0 = kt * 64;
        __syncthreads();
#pragma unroll
        for (int jj = 0; jj < 2; ++jj) {
            int chunk = w * 2 + jj;
            int row = chunk * 8 + srow;
            int cs = sc_ ^ (row & 7);
            ldsdma16(&As[chunk * 512], &A[(m0 + row) * 1024 + k0 + cs * 8]);
        }
#pragma unroll
        for (int jj = 0; jj < 4; ++jj) {
            int chunk = w * 4 + jj;
            int row = chunk * 8 + srow;
            int cs = sc_ ^ (row & 7);
            ldsdma16(&Bs[chunk * 512], &W[(e0 + row) * 1024 + k0 + cs * 8]);
        }
        __syncthreads();
#pragma unroll
        for (int kk = 0; kk < 64; kk += 32) {
            const int cb = kk >> 3;
            bf16x8 af[4], bfr[2];
#pragma unroll
            for (int i = 0; i < 4; ++i) {
                int r = i * 16 + l15;
                af[i] = ld8(&As[r * 64 + (((cb + grp) ^ (r & 7)) << 3)]);
            }
#pragma unroll
            for (int j = 0; j < 2; ++j) {
                int r = w * 32 + j * 16 + l15;
                bfr[j] = ld8(&Bs[r * 64 + (((cb + grp) ^ (r & 7)) << 3)]);
            }
#pragma unroll
            for (int i = 0; i < 4; ++i)
#pragma unroll
                for (int j = 0; j < 2; ++j)
                    acc[i][j] = __builtin_amdgcn_mfma_f32_16x16x32_bf16(
                        af[i], bfr[j], acc[i][j], 0, 0, 0);
        }
    }

#pragma unroll
    for (int j = 0; j < 2; ++j) {
        int e = e0 + w * 32 + j * 16 + l15;
        float bv_ = bias[e];
#pragma unroll
        for (int i = 0; i < 4; ++i)
#pragma unroll
            for (int r = 0; r < 4; ++r) {
                int jl = (m0 & 2047) + i * 16 + grp * 4 + r;
                if (jl < nbl) {
                    int s = sidx[b * 2048 + jl];
                    out[(size_t)(b * 2048 + s) * 1024 + e] = acc[i][j][r] + bv_;
                }
            }
    }
}

extern "C" void kernel_launch(void* const* d_in, const int* in_sizes, int n_in,
                              void* d_out, int out_size, void* d_ws, size_t ws_size,
                              hipStream_t stream) {
    const float* x    = (const float*)d_in[0];
    const float* mask = (const float*)d_in[1];
    const float* Wq   = (const float*)d_in[2];
    const float* bq   = (const float*)d_in[3];
    const float* Wk   = (const float*)d_in[4];
    const float* bk   = (const float*)d_in[5];
    const float* Wv   = (const float*)d_in[6];
    const float* bv   = (const float*)d_in[7];
    const float* Wo   = (const float*)d_in[8];
    const float* bo   = (const float*)d_in[9];
    float* out = (float*)d_out;

    unsigned short* Qc   = (unsigned short*)d_ws;    // u16 element offsets:
    unsigned short* Kc   = Qc + 4194304;
    unsigned short* VTc  = Qc + 8388608;
    unsigned short* XcXa = Qc + 12582912;            // Xc (prep->qkv), then Xattn
    unsigned short* Wb   = Qc + 16777216;
    int* sidx            = (int*)(Qc + 20971520);    // 4096 ints
    int* hdr             = sidx + 4096;              // nb[2], nbp[2]

    compact_kernel<<<dim3(2), 256, 0, stream>>>(mask, sidx, hdr);
    prep_kernel<<<dim3(12288), 256, 0, stream>>>(x, mask, Wq, Wk, Wv, Wo, bo,
                                                 sidx, hdr, XcXa, Wb, out);
    qkv_kernel<<<dim3(32, 24), 256, 0, stream>>>(XcXa, Wb, bq, bk, bv, hdr,
                                                 Qc, Kc, VTc);
    attn_kernel<<<dim3(32, 32), 512, 0, stream>>>(Qc, Kc, VTc, hdr, XcXa);
    oproj_kernel<<<dim3(64, 8), 256, 0, stream>>>(XcXa, Wb + 3145728, bo,
                                                  sidx, hdr, out);
}

// Round 18
// 178.235 us; speedup vs baseline: 1.0529x; 1.0529x over previous
//
#include <hip/hip_runtime.h>
#include <stdint.h>

#define DEV __device__ __forceinline__

typedef __attribute__((ext_vector_type(4))) float f32x4;
typedef __attribute__((ext_vector_type(16))) float f32x16;
typedef __attribute__((ext_vector_type(8))) __bf16 bf16x8;
typedef __attribute__((ext_vector_type(4))) __bf16 bf16x4;
typedef __attribute__((ext_vector_type(8))) short short8;
typedef __attribute__((ext_vector_type(4))) unsigned short u16x4;

DEV unsigned short f2bf_n(float f) {
    __bf16 h = (__bf16)f;
    return __builtin_bit_cast(unsigned short, h);
}
DEV bf16x8 ld8(const unsigned short* p) {
    short8 v = *(const short8*)p;
    return __builtin_bit_cast(bf16x8, v);
}
DEV void ldsdma16(unsigned short* lds, const unsigned short* g) {
    __builtin_amdgcn_global_load_lds(
        (const __attribute__((address_space(1))) unsigned int*)g,
        (__attribute__((address_space(3))) unsigned int*)lds, 16, 0, 0);
}

// ---------------------------------------------------------------------------
// Token compaction with parallel (Hillis-Steele) scan.
// sidx[b][j] = s of j-th unmasked token; hdr[b]=nb, hdr[2+b]=nbp (pad 128).
// ---------------------------------------------------------------------------
__global__ __launch_bounds__(256) void compact_kernel(
    const float* __restrict__ mask, int* __restrict__ sidx, int* __restrict__ hdr)
{
    __shared__ int part[256];
    const int b = blockIdx.x, t = threadIdx.x;
    int loc[8], cnt = 0;
#pragma unroll
    for (int k = 0; k < 8; ++k) {
        loc[k] = (mask[b * 2048 + t * 8 + k] > 0.5f) ? 1 : 0;
        cnt += loc[k];
    }
    part[t] = cnt;
    __syncthreads();
#pragma unroll
    for (int off = 1; off < 256; off <<= 1) {
        int v = (t >= off) ? part[t - off] : 0;
        __syncthreads();
        part[t] += v;
        __syncthreads();
    }
    const int total = part[255];
    if (t == 0) {
        hdr[b] = total;
        hdr[2 + b] = (total + 127) & ~127;
    }
    int base = part[t] - cnt;            // exclusive prefix
#pragma unroll
    for (int k = 0; k < 8; ++k)
        if (loc[k]) sidx[b * 2048 + (base++)] = t * 8 + k;
    for (int j = total + t; j < 2048; j += 256) sidx[b * 2048 + j] = -1;
}

// ---------------------------------------------------------------------------
// Fused prep: grid 12288 blocks x 256 thr, three block ranges co-scheduled:
//   [0,4096)     gather+convert X row -> compact Xc (zero pad rows)
//   [4096,8192)  out init: every token's out row = bo
//   [8192,12288) W f32 -> bf16 (Wq|Wk|Wv|Wo)
// ---------------------------------------------------------------------------
__global__ __launch_bounds__(256) void prep_kernel(
    const float* __restrict__ X, const float* __restrict__ mask_unused,
    const float* __restrict__ Wq, const float* __restrict__ Wk,
    const float* __restrict__ Wv, const float* __restrict__ Wo,
    const float* __restrict__ bo, const int* __restrict__ sidx,
    const int* __restrict__ hdr,
    unsigned short* __restrict__ Xc, unsigned short* __restrict__ Wb,
    float* __restrict__ out)
{
    const int bx = blockIdx.x, t = threadIdx.x;
    if (bx < 4096) {
        const int b = bx >> 11, j = bx & 2047;
        if (j >= hdr[2 + b]) return;
        const int col = t * 4;
        bf16x4 o;
        if (j < hdr[b]) {
            int s = sidx[b * 2048 + j];
            f32x4 v = *(const f32x4*)&X[(size_t)(b * 2048 + s) * 1024 + col];
            o = (bf16x4){ (__bf16)v[0], (__bf16)v[1], (__bf16)v[2], (__bf16)v[3] };
        } else {
            o = (bf16x4){ (__bf16)0.f, (__bf16)0.f, (__bf16)0.f, (__bf16)0.f };
        }
        *(bf16x4*)&Xc[(size_t)bx * 1024 + col] = o;
    } else if (bx < 8192) {
        int row = bx - 4096;
        int e = t * 4;
        f32x4 v = *(const f32x4*)&bo[e];
        *(f32x4*)&out[(size_t)row * 1024 + e] = v;
    } else {
        int c = (bx - 8192) * 256 + t;
        int wsel = c >> 18, off = (c & 262143) * 4;
        const float* ws_[4] = { Wq, Wk, Wv, Wo };
        f32x4 v = *(const f32x4*)(ws_[wsel] + off);
        bf16x4 b = { (__bf16)v[0], (__bf16)v[1], (__bf16)v[2], (__bf16)v[3] };
        *(bf16x4*)&Wb[wsel * 1048576 + off] = b;
    }
}

// ---------------------------------------------------------------------------
// Fused QKV projection on COMPACT rows (256 thr, BK=64 single-buffer DMA
// staging). Blocks beyond nbp(b) exit. grid (32, 24).
// ---------------------------------------------------------------------------
__global__ __launch_bounds__(256) void qkv_kernel(
    const unsigned short* __restrict__ Xc, const unsigned short* __restrict__ Wb,
    const float* __restrict__ bq, const float* __restrict__ bk,
    const float* __restrict__ bv, const int* __restrict__ hdr,
    unsigned short* __restrict__ Qc, unsigned short* __restrict__ Kc,
    unsigned short* __restrict__ VTc)
{
    __shared__ __align__(16) unsigned short SMEM[17408];
    unsigned short* As = SMEM;
    unsigned short* Bs = SMEM + 8192;

    const int m0 = blockIdx.x * 128;
    const int b = m0 >> 11;
    if ((m0 & 2047) >= hdr[2 + b]) return;

    const int t = threadIdx.x;
    const int lane = t & 63, w = t >> 6;
    const int wm = w & 1, wn = w >> 1;
    const int l15 = lane & 15, grp = lane >> 4;
    const int which = blockIdx.y >> 3;
    const int e0 = (blockIdx.y & 7) * 128;

    const unsigned short* Wmat = Wb + which * 1048576;
    const float* bias = (which == 0) ? bq : (which == 1) ? bk : bv;

    const int srow = lane >> 3, sc_ = lane & 7;

    f32x4 acc[4][4];
#pragma unroll
    for (int i = 0; i < 4; ++i)
#pragma unroll
        for (int j = 0; j < 4; ++j) acc[i][j] = (f32x4){0.f, 0.f, 0.f, 0.f};

    for (int kt = 0; kt < 16; ++kt) {
        const int k0 = kt * 64;
        __syncthreads();
#pragma unroll
        for (int j = 0; j < 4; ++j) {
            int row = (w * 4 + j) * 8 + srow;
            int cs = sc_ ^ (row & 7);
            ldsdma16(&As[(w * 4 + j) * 512],
                     &Xc[(m0 + row) * 1024 + k0 + cs * 8]);
            ldsdma16(&Bs[(w * 4 + j) * 512],
                     &Wmat[(e0 + row) * 1024 + k0 + cs * 8]);
        }
        __syncthreads();
#pragma unroll
        for (int kk = 0; kk < 64; kk += 32) {
            const int cb = kk >> 3;
            bf16x8 af[4], bfr[4];
#pragma unroll
            for (int i = 0; i < 4; ++i) {
                int r = wm * 64 + i * 16 + l15;
                af[i] = ld8(&As[r * 64 + (((cb + grp) ^ (r & 7)) << 3)]);
            }
#pragma unroll
            for (int j = 0; j < 4; ++j) {
                int r = wn * 64 + j * 16 + l15;
                bfr[j] = ld8(&Bs[r * 64 + (((cb + grp) ^ (r & 7)) << 3)]);
            }
#pragma unroll
            for (int i = 0; i < 4; ++i)
#pragma unroll
                for (int j = 0; j < 4; ++j)
                    acc[i][j] = __builtin_amdgcn_mfma_f32_16x16x32_bf16(
                        af[i], bfr[j], acc[i][j], 0, 0, 0);
        }
    }

    __syncthreads();

    if (which == 2) {
#pragma unroll
        for (int j = 0; j < 4; ++j) {
            int e = e0 + wn * 64 + j * 16 + l15;
            float bv_ = bias[e];
#pragma unroll
            for (int i = 0; i < 4; ++i) {
                u16x4 pk;
#pragma unroll
                for (int r = 0; r < 4; ++r) pk[r] = f2bf_n(acc[i][j][r] + bv_);
                *(u16x4*)&SMEM[(wn * 64 + j * 16 + l15) * 136 +
                               wm * 64 + i * 16 + grp * 4] = pk;
            }
        }
        __syncthreads();
        const int s0 = m0 & 2047;
#pragma unroll
        for (int round = 0; round < 8; ++round) {
            int dhl = (t >> 4) + round * 16;
            int chunk = t & 15;
            int h = (e0 + dhl) >> 6, dh = (e0 + dhl) & 63;
            *(short8*)&VTc[((b * 16 + h) * 64 + dh) * 2048 + s0 + chunk * 8] =
                *(const short8*)&SMEM[dhl * 136 + chunk * 8];
        }
    } else {
        const float scale = (which == 0) ? 0.125f : 1.0f;
#pragma unroll
        for (int j = 0; j < 4; ++j) {
            int e = e0 + wn * 64 + j * 16 + l15;
            float bv_ = bias[e];
#pragma unroll
            for (int i = 0; i < 4; ++i)
#pragma unroll
                for (int r = 0; r < 4; ++r)
                    SMEM[(wm * 64 + i * 16 + grp * 4 + r) * 136 +
                         wn * 64 + j * 16 + l15] =
                        f2bf_n((acc[i][j][r] + bv_) * scale);
        }
        __syncthreads();
        unsigned short* dst = (which == 0) ? Qc : Kc;
#pragma unroll
        for (int round = 0; round < 8; ++round) {
            int tl = (t >> 4) + round * 16;
            int chunk = t & 15;
            int e = e0 + chunk * 8;
            int h = e >> 6, dh = e & 63;
            int s = (m0 & 2047) + tl;
            *(short8*)&dst[((b * 16 + h) * 2048 + s) * 64 + dh] =
                *(const short8*)&SMEM[tl * 136 + chunk * 8];
        }
    }
}

// ---------------------------------------------------------------------------
// Flash attention v5-compact (round-16 verbatim — best measured):
// 32x32x16 + 2-way split-K + half-width Ps. 128 q-rows/block (staging
// amortization sweet spot; 64-row variant doubled staging per q-row and
// regressed — round 17). kb loop to nbp/128; key mask = (j < nb).
// grid (16, 32), 512 thr, wave = (khalf=w>>2, qg=w&3). LDS 53,248 B.
// ---------------------------------------------------------------------------
__global__ __launch_bounds__(512, 4) void attn_kernel(
    const unsigned short* __restrict__ Qc, const unsigned short* __restrict__ Kc,
    const unsigned short* __restrict__ VTc, const int* __restrict__ hdr,
    unsigned short* __restrict__ Xattn)
{
    __shared__ __align__(16) unsigned short SMEM[26624];   // 53,248 B
    unsigned short* Ks = SMEM;
    unsigned short* Vs = SMEM + 8192;
    unsigned short* Ps = SMEM + 16384;
    float* mrg = (float*)SMEM;

    const int bh = blockIdx.y;
    const int b = bh >> 4;
    const int nbl = hdr[b], nbpl = hdr[2 + b];
    const int q0 = blockIdx.x * 128;
    if (q0 >= nbpl) return;

    const int t = threadIdx.x;
    const int lane = t & 63, w = t >> 6;
    const int l31 = lane & 31, half = lane >> 5;
    const int qg = w & 3, khalf = w >> 2;

    const unsigned short* Kp = Kc + (size_t)bh * 131072;
    const unsigned short* Vp = VTc + (size_t)bh * 131072;

    bf16x8 qf[4];
#pragma unroll
    for (int s = 0; s < 4; ++s)
        qf[s] = ld8(&Qc[(bh * 2048 + q0 + qg * 32 + l31) * 64 + s * 16 + half * 8]);

    short onev = (l31 == 0) ? (short)0x3F80 : (short)0;
    short8 ov = { onev, onev, onev, onev, onev, onev, onev, onev };
    bf16x8 ones_f = __builtin_bit_cast(bf16x8, ov);

    unsigned short* Pw = Ps + w * 1280;

    f32x16 accd[2], accl;
#pragma unroll
    for (int d = 0; d < 2; ++d)
#pragma unroll
        for (int r = 0; r < 16; ++r) accd[d][r] = 0.f;
#pragma unroll
    for (int r = 0; r < 16; ++r) accl[r] = 0.f;

    const int nkb = nbpl >> 7;
    for (int kb = 0; kb < nkb; ++kb) {
        const int k0 = kb * 128;
        __syncthreads();
#pragma unroll
        for (int ii = 0; ii < 2; ++ii) {
            int inst = w * 2 + ii;
            int row = inst * 8 + (lane >> 3);
            int cs = (lane & 7) ^ (row & 7);
            ldsdma16(&Ks[inst * 512], &Kp[(k0 + row) * 64 + cs * 8]);
        }
#pragma unroll
        for (int ii = 0; ii < 2; ++ii) {
            int inst = w * 2 + ii;
            int row = inst * 4 + (lane >> 4);
            int cs = (lane & 15) ^ (row & 15);
            ldsdma16(&Vs[inst * 512], &Vp[row * 2048 + k0 + cs * 8]);
        }
        float mc[2];
#pragma unroll
        for (int g = 0; g < 2; ++g)
            mc[g] = (k0 + khalf * 64 + g * 32 + l31 < nbl) ? 1.f : 0.f;
        __syncthreads();

#pragma unroll
        for (int g = 0; g < 2; ++g) {
            f32x16 z;
#pragma unroll
            for (int r = 0; r < 16; ++r) z[r] = 0.f;
            int rK = khalf * 64 + g * 32 + l31;
#pragma unroll
            for (int s = 0; s < 4; ++s) {
                int chunk = s * 2 + half;
                bf16x8 kf = ld8(&Ks[rK * 64 + ((chunk ^ (rK & 7)) << 3)]);
                z = __builtin_amdgcn_mfma_f32_32x32x16_bf16(qf[s], kf, z, 0, 0, 0);
            }
#pragma unroll
            for (int r = 0; r < 16; ++r) {
                float p = __expf(z[r]) * mc[g];
                int ql = (r & 3) + 8 * (r >> 2) + 4 * half;
                Pw[ql * 40 + l31] = f2bf_n(p);
            }
            bf16x8 pf[2];
#pragma unroll
            for (int sp = 0; sp < 2; ++sp)
                pf[sp] = ld8(&Pw[l31 * 40 + sp * 16 + half * 8]);
#pragma unroll
            for (int d = 0; d < 2; ++d) {
                int rV = d * 32 + l31;
#pragma unroll
                for (int sp = 0; sp < 2; ++sp) {
                    int chunk = khalf * 8 + g * 4 + sp * 2 + half;
                    bf16x8 vf = ld8(&Vs[rV * 128 + ((chunk ^ (rV & 15)) << 3)]);
                    accd[d] = __builtin_amdgcn_mfma_f32_32x32x16_bf16(
                        pf[sp], vf, accd[d], 0, 0, 0);
                }
            }
#pragma unroll
            for (int sp = 0; sp < 2; ++sp)
                accl = __builtin_amdgcn_mfma_f32_32x32x16_bf16(
                    pf[sp], ones_f, accl, 0, 0, 0);
        }
    }

    __syncthreads();
    if (khalf == 1) {
        float* q_ = mrg + qg * 3072;
#pragma unroll
        for (int r = 0; r < 16; ++r) {
            q_[(r) * 64 + lane]      = accd[0][r];
            q_[(16 + r) * 64 + lane] = accd[1][r];
            q_[(32 + r) * 64 + lane] = accl[r];
        }
    }
    __syncthreads();
    if (khalf == 0) {
        const float* q_ = mrg + qg * 3072;
#pragma unroll
        for (int r = 0; r < 16; ++r) {
            accd[0][r] += q_[(r) * 64 + lane];
            accd[1][r] += q_[(16 + r) * 64 + lane];
            accl[r]    += q_[(32 + r) * 64 + lane];
        }
#pragma unroll
        for (int r = 0; r < 16; ++r) {
            int ql = (r & 3) + 8 * (r >> 2) + 4 * half;
            int j = q0 + qg * 32 + ql;
            float lr = __shfl(accl[r], half * 32, 64);
            float inv = 1.f / (lr + 1e-13f);
#pragma unroll
            for (int d = 0; d < 2; ++d)
                Xattn[(b * 2048 + j) * 1024 + (bh & 15) * 64 + d * 32 + l31] =
                    f2bf_n(accd[d][r] * inv);
        }
    }
}

// ---------------------------------------------------------------------------
// Output projection on COMPACT rows, scatter via sidx. grid (64, 8).
// ---------------------------------------------------------------------------
__global__ __launch_bounds__(256) void oproj_kernel(
    const unsigned short* __restrict__ A, const unsigned short* __restrict__ W,
    const float* __restrict__ bias, const int* __restrict__ sidx,
    const int* __restrict__ hdr, float* __restrict__ out)
{
    __shared__ __align__(16) unsigned short As[64 * 64];
    __shared__ __align__(16) unsigned short Bs[128 * 64];

    const int m0 = blockIdx.x * 64;
    const int b = m0 >> 11;
    const int nbl = hdr[b];
    if ((m0 & 2047) >= hdr[2 + b]) return;

    const int t = threadIdx.x;
    const int lane = t & 63, w = t >> 6;
    const int l15 = lane & 15, grp = lane >> 4;
    const int e0 = blockIdx.y * 128;
    const int srow = lane >> 3, sc_ = lane & 7;

    f32x4 acc[4][2];
#pragma unroll
    for (int i = 0; i < 4; ++i)
#pragma unroll
        for (int j = 0; j < 2; ++j) acc[i][j] = (f32x4){0.f, 0.f, 0.f, 0.f};

    for (int kt = 0; kt < 16; ++kt) {
        const int k0 = kt * 64;
        __syncthreads();
#pragma unroll
        for (int jj = 0; jj < 2; ++jj) {
            int chunk = w * 2 + jj;
            int row = chunk * 8 + srow;
            int cs = sc_ ^ (row & 7);
            ldsdma16(&As[chunk * 512], &A[(m0 + row) * 1024 + k0 + cs * 8]);
        }
#pragma unroll
        for (int jj = 0; jj < 4; ++jj) {
            int chunk = w * 4 + jj;
            int row = chunk * 8 + srow;
            int cs = sc_ ^ (row & 7);
            ldsdma16(&Bs[chunk * 512], &W[(e0 + row) * 1024 + k0 + cs * 8]);
        }
        __syncthreads();
#pragma unroll
        for (int kk = 0; kk < 64; kk += 32) {
            const int cb = kk >> 3;
            bf16x8 af[4], bfr[2];
#pragma unroll
            for (int i = 0; i < 4; ++i) {
                int r = i * 16 + l15;
                af[i] = ld8(&As[r * 64 + (((cb + grp) ^ (r & 7)) << 3)]);
            }
#pragma unroll
            for (int j = 0; j < 2; ++j) {
                int r = w * 32 + j * 16 + l15;
                bfr[j] = ld8(&Bs[r * 64 + (((cb + grp) ^ (r & 7)) << 3)]);
            }
#pragma unroll
            for (int i = 0; i < 4; ++i)
#pragma unroll
                for (int j = 0; j < 2; ++j)
                    acc[i][j] = __builtin_amdgcn_mfma_f32_16x16x32_bf16(
                        af[i], bfr[j], acc[i][j], 0, 0, 0);
        }
    }

#pragma unroll
    for (int j = 0; j < 2; ++j) {
        int e = e0 + w * 32 + j * 16 + l15;
        float bv_ = bias[e];
#pragma unroll
        for (int i = 0; i < 4; ++i)
#pragma unroll
            for (int r = 0; r < 4; ++r) {
                int jl = (m0 & 2047) + i * 16 + grp * 4 + r;
                if (jl < nbl) {
                    int s = sidx[b * 2048 + jl];
                    out[(size_t)(b * 2048 + s) * 1024 + e] = acc[i][j][r] + bv_;
                }
            }
    }
}

extern "C" void kernel_launch(void* const* d_in, const int* in_sizes, int n_in,
                              void* d_out, int out_size, void* d_ws, size_t ws_size,
                              hipStream_t stream) {
    const float* x    = (const float*)d_in[0];
    const float* mask = (const float*)d_in[1];
    const float* Wq   = (const float*)d_in[2];
    const float* bq   = (const float*)d_in[3];
    const float* Wk   = (const float*)d_in[4];
    const float* bk   = (const float*)d_in[5];
    const float* Wv   = (const float*)d_in[6];
    const float* bv   = (const float*)d_in[7];
    const float* Wo   = (const float*)d_in[8];
    const float* bo   = (const float*)d_in[9];
    float* out = (float*)d_out;

    unsigned short* Qc   = (unsigned short*)d_ws;    // u16 element offsets:
    unsigned short* Kc   = Qc + 4194304;
    unsigned short* VTc  = Qc + 8388608;
    unsigned short* XcXa = Qc + 12582912;            // Xc (prep->qkv), then Xattn
    unsigned short* Wb   = Qc + 16777216;
    int* sidx            = (int*)(Qc + 20971520);    // 4096 ints
    int* hdr             = sidx + 4096;              // nb[2], nbp[2]

    compact_kernel<<<dim3(2), 256, 0, stream>>>(mask, sidx, hdr);
    prep_kernel<<<dim3(12288), 256, 0, stream>>>(x, mask, Wq, Wk, Wv, Wo, bo,
                                                 sidx, hdr, XcXa, Wb, out);
    qkv_kernel<<<dim3(32, 24), 256, 0, stream>>>(XcXa, Wb, bq, bk, bv, hdr,
                                                 Qc, Kc, VTc);
    attn_kernel<<<dim3(16, 32), 512, 0, stream>>>(Qc, Kc, VTc, hdr, XcXa);
    oproj_kernel<<<dim3(64, 8), 256, 0, stream>>>(XcXa, Wb + 3145728, bo,
                                                  sidx, hdr, out);
}